// Round 6
// baseline (123.212 us; speedup 1.0000x reference)
//
#include <hip/hip_runtime.h>
#include <math.h>

#define BB 4
#define NN 2048
#define FF 128
#define HH 4
#define DD 32
#define NEG_SLOPE 0.2f
#define LOG2E 1.4426950408889634f

typedef __attribute__((ext_vector_type(8))) short short8;
typedef __attribute__((ext_vector_type(4))) float floatx4;
typedef __attribute__((ext_vector_type(2))) float floatx2;

__device__ __forceinline__ float exp2_fast(float x) {
#if __has_builtin(__builtin_amdgcn_exp2f)
    return __builtin_amdgcn_exp2f(x);
#else
    return exp2f(x);
#endif
}

__device__ __forceinline__ int bit_mask(unsigned int w, int bit) {
#if __has_builtin(__builtin_amdgcn_sbfe)
    return __builtin_amdgcn_sbfe((int)w, bit, 1);    // v_bfe_i32: 0 or -1
#else
    return ((int)(w << (31 - bit))) >> 31;
#endif
}

// pack two fp32 -> one u32 holding (bf16(hi)<<16 | bf16(lo)), RTNE
__device__ __forceinline__ unsigned int pack2_rtne(float lo, float hi) {
    unsigned int ul = __float_as_uint(lo); ul += 0x7FFFu + ((ul >> 16) & 1u);
    unsigned int uh = __float_as_uint(hi); uh += 0x7FFFu + ((uh >> 16) & 1u);
    return (ul >> 16) | (uh & 0xFFFF0000u);
}

// ---------------- K1: prep = {MFMA gemm_fused (blocks 0..511), pack_adj (512..1023)}
// (unchanged from R5; ed_t stores precomputed exp-pairs as float2)
__global__ __launch_bounds__(256) void k_prep(const float* __restrict__ x,
                                              const float* __restrict__ W,
                                              const float* __restrict__ a_src,
                                              const float* __restrict__ a_dst,
                                              const int* __restrict__ adj,
                                              unsigned short* __restrict__ ht,
                                              float* __restrict__ es_t,
                                              float* __restrict__ ed_t,
                                              unsigned int* __restrict__ bits) {
    __shared__ unsigned short wbf[128][144];   // 36.9 KB, W as bf16 [o][i]
    __shared__ unsigned short hbf[128][24];    // 6 KB, h^T as bf16 [o][m_local]
    __shared__ float vs_s[HH][FF], vd_s[HH][FF];   // 4 KB
    __shared__ float as_s[FF], ad_s[FF];           // 1 KB
    int t = threadIdx.x;

    if (blockIdx.x >= 512) {
        // ---- pack_adj ----
        int idx = (blockIdx.x - 512) * 256 + t;
        int n = idx >> 6, w = idx & 63;
        const int4* base = (const int4*)(adj + (size_t)n * NN + w * 32);
        unsigned int word = 0;
#pragma unroll
        for (int q = 0; q < 8; ++q) {
            int4 a = base[q];
            word |= ((unsigned int)(a.x & 1)) << (q * 4 + 0);
            word |= ((unsigned int)(a.y & 1)) << (q * 4 + 1);
            word |= ((unsigned int)(a.z & 1)) << (q * 4 + 2);
            word |= ((unsigned int)(a.w & 1)) << (q * 4 + 3);
        }
        bits[idx] = word;
        return;
    }

    int m0g = blockIdx.x * 16;
    int b = m0g >> 11;
    int m_block = m0g & 2047;

    if (t < FF) { as_s[t] = a_src[t]; ad_s[t] = a_dst[t]; }
    // stage W -> bf16 LDS: 2048 chunks of 8 shorts
#pragma unroll
    for (int k = 0; k < 8; ++k) {
        int idx = t + k * 256;
        int row = idx >> 4, ch = idx & 15;           // 16 chunks of 8 per row
        const float* wp = W + (size_t)row * FF + ch * 8;
        float4 v0 = *(const float4*)wp;
        float4 v1 = *(const float4*)(wp + 4);
        unsigned int u[4];
        u[0] = pack2_rtne(v0.x, v0.y); u[1] = pack2_rtne(v0.z, v0.w);
        u[2] = pack2_rtne(v1.x, v1.y); u[3] = pack2_rtne(v1.z, v1.w);
        *(int4*)&wbf[row][ch * 8] = *(const int4*)u;
    }
    __syncthreads();

    // per-head column sums: vs[h][i] = sum_d W[h*32+d][i]*a_src[h][d]
    {
        int i = t & 127;
        float acc4[4] = {0.f, 0.f, 0.f, 0.f};
        if (t < 128) {
            for (int o = 0; o < 128; ++o) {
                float wv = __uint_as_float(((unsigned int)wbf[o][i]) << 16);
                acc4[o >> 5] += wv * as_s[o];
            }
#pragma unroll
            for (int hd = 0; hd < 4; ++hd) vs_s[hd][i] = acc4[hd];
        } else {
            for (int o = 0; o < 128; ++o) {
                float wv = __uint_as_float(((unsigned int)wbf[o][i]) << 16);
                acc4[o >> 5] += wv * ad_s[o];
            }
#pragma unroll
            for (int hd = 0; hd < 4; ++hd) vd_s[hd][i] = acc4[hd];
        }
    }

    // MFMA: h[m0g..+15][0..127] ; wave wid does col-tiles c=wid*2, wid*2+1
    int wid = t >> 6, lane = t & 63;
    int r = lane & 15, q = lane >> 4;
    floatx4 acc[2] = {{0.f,0.f,0.f,0.f},{0.f,0.f,0.f,0.f}};
    const float* xrow = x + (size_t)(m0g + r) * FF + q * 8;
#pragma unroll
    for (int kk = 0; kk < 4; ++kk) {
        float4 a0 = *(const float4*)(xrow + kk * 32);
        float4 a1 = *(const float4*)(xrow + kk * 32 + 4);
        union { short8 s8; unsigned int u[4]; } af;
        af.u[0] = pack2_rtne(a0.x, a0.y); af.u[1] = pack2_rtne(a0.z, a0.w);
        af.u[2] = pack2_rtne(a1.x, a1.y); af.u[3] = pack2_rtne(a1.z, a1.w);
#pragma unroll
        for (int c = 0; c < 2; ++c) {
            int o = (wid * 2 + c) * 16 + r;          // B col = lane&15
            short8 bf = *(const short8*)&wbf[o][kk * 32 + q * 8];
            acc[c] = __builtin_amdgcn_mfma_f32_16x16x32_bf16(af.s8, bf, acc[c], 0, 0, 0);
        }
    }
    // store h^T (bf16) to LDS: lane holds col o, rows q*4+reg
#pragma unroll
    for (int c = 0; c < 2; ++c) {
        int o = (wid * 2 + c) * 16 + r;
        unsigned int u2[2];
        u2[0] = pack2_rtne(acc[c][0], acc[c][1]);
        u2[1] = pack2_rtne(acc[c][2], acc[c][3]);
        *(int2*)&hbf[o][q * 4] = *(const int2*)u2;
    }
    __syncthreads();

    // ht write: thread t<128 handles col o=t -> ht[b*4+hd][d][m_block..+15]
    if (t < 128) {
        int hd = t >> 5, d = t & 31;
        unsigned short* op = ht + ((size_t)(b * HH + hd) * DD + d) * NN + m_block;
        *(int4*)op       = *(const int4*)&hbf[t][0];
        *(int4*)(op + 8) = *(const int4*)&hbf[t][8];
    }
    // es/ed in fp32: thread (m = t>>4, sg = t&15), partial over i = sg*8..+7
    {
        int m = t >> 4, sg = t & 15;
        const float* xp = x + (size_t)(m0g + m) * FF + sg * 8;
        float4 x0 = *(const float4*)xp;
        float4 x1 = *(const float4*)(xp + 4);
#pragma unroll
        for (int hd = 0; hd < 4; ++hd) {
            const float* vsp = &vs_s[hd][sg * 8];
            const float* vdp = &vd_s[hd][sg * 8];
            float es = x0.x * vsp[0] + x0.y * vsp[1] + x0.z * vsp[2] + x0.w * vsp[3]
                     + x1.x * vsp[4] + x1.y * vsp[5] + x1.z * vsp[6] + x1.w * vsp[7];
            float ed = x0.x * vdp[0] + x0.y * vdp[1] + x0.z * vdp[2] + x0.w * vdp[3]
                     + x1.x * vdp[4] + x1.y * vdp[5] + x1.z * vdp[6] + x1.w * vdp[7];
#pragma unroll
            for (int k = 1; k < 16; k <<= 1) {
                es += __shfl_xor(es, k);
                ed += __shfl_xor(ed, k);
            }
            if (sg == 0) {
                size_t eb = (size_t)(b * HH + hd) * NN + m_block + m;
                es_t[eb] = es * LOG2E;
                float ee = ed * LOG2E;
                float2 pr;
                pr.x = exp2_fast(ee);
                pr.y = exp2_fast(NEG_SLOPE * ee);
                *(float2*)(ed_t + eb * 2) = pr;
            }
        }
    }
}

// ---------------- K2 (v6): same verified inner math as R4/R5; co-residency
// pushed 2 -> 3 blocks/CU (R5's confirmed lever was grid-limited at 2):
//  - grid (64,16) = 1024 blocks x 512 thr, 32 rows/block,
//    8 waves = 2 n-groups x 4 K-quarters (512 m each, 16 c-iters/wave).
//  - hb staged in 4 chunks of 128 m per quarter: 35.1 KB; + ep 16.4 KB
//    = 51.5 KB/block -> 3 blocks/CU = 24 waves/CU (6/SIMD).
//  - row stride 548 shorts = 274 dw === 18 (mod 32): all 16 r-lanes start on
//    distinct banks (R5's 264 dw === 8 gave 4-way conflicts on b0/b1 reads).
//  - 4-way K-quarter reduction tail (quarters 1-3 store, quarter 0 adds).
#define HBW 548    // hb row stride in shorts
#define QOF 136    // per-quarter column offset (128 data + 8 pad shorts)
__global__ __launch_bounds__(512, 6) void k_attn(
        const unsigned short* __restrict__ ht,
        const unsigned int* __restrict__ bits,
        const float* __restrict__ es_t,
        const float* __restrict__ ed_t,
        float* __restrict__ out) {
    __shared__ unsigned short hb[DD * HBW];   // 35,072 B
    __shared__ float ep[NN * 2];               // 16,384 B: (Ed_p, Ed_n) pairs
    int t = threadIdx.x;
    int n0 = blockIdx.x * 32;
    int bh = blockIdx.y;
    int b = bh >> 2, head = bh & 3;

    int wid = t >> 6, lane = t & 63;
    int q = lane >> 4, r = lane & 15;
    int qo = q * 8;
    int qt = wid >> 1, ng = wid & 1;   // K-quarter, n-group
    int n_l = ng * 16 + r;

    const unsigned short* htp = ht + (size_t)bh * DD * NN;

    // ep copy: 1024 float4 over 512 threads (pairs precomputed in k_prep)
    {
        const float4* src = (const float4*)(ed_t + (size_t)bh * NN * 2);
        ((float4*)ep)[t]       = src[t];
        ((float4*)ep)[t + 512] = src[t + 512];
    }
    // stage chunk 0: [32 d][4 quarters x 128 m] = 2048 int4 over 512 thr
#pragma unroll
    for (int k2 = 0; k2 < 4; ++k2) {
        int j = t + k2 * 512;
        int qq = j >> 9, jj = j & 511;      // quarter, then 512 int4 within
        int d = jj >> 4, c16 = jj & 15;     // 16 int4 per d-row (128 m)
        int4 v = *(const int4*)(htp + (size_t)d * NN + qq * 512 + c16 * 8);
        *(int4*)&hb[d * HBW + qq * QOF + c16 * 8] = v;
    }
    float esv = es_t[(size_t)bh * NN + n0 + n_l];   // already * log2e
    float tn = exp2_fast(-0.8f * esv);              // es_n/es_p, row-constant
    __syncthreads();

    floatx4 acc0 = {0.f, 0.f, 0.f, 0.f};
    floatx4 acc1 = {0.f, 0.f, 0.f, 0.f};
    floatx4 accd = {0.f, 0.f, 0.f, 0.f};
    union { short8 s8; int i[4]; } ones;
    ones.i[0] = 0x3F803F80; ones.i[1] = 0x3F803F80;
    ones.i[2] = 0x3F803F80; ones.i[3] = 0x3F803F80;

    const unsigned short* hrow0 = &hb[r * HBW + qt * QOF + qo];
    const unsigned short* hrow1 = &hb[(r + 16) * HBW + qt * QOF + qo];
    const unsigned int* bpb = bits + (size_t)(n0 + n_l) * 64 + qt * 16;

    for (int ck = 0; ck < 4; ++ck) {
        int4 bwv = *(const int4*)(bpb + ck * 4);       // 4 words = 128 m
        const float* pb_ck = ep + (qt * 512 + ck * 128) * 2;
#pragma unroll
        for (int c = 0; c < 4; ++c) {
            unsigned int word = (unsigned int)((&bwv.x)[c]);
            int mb = c * 32;                           // chunk-local m offset
            unsigned int wq = word >> qo;
            const float* pbase = pb_ck + (mb + qo) * 2;
            union { short8 s8; int i[4]; } af;
#pragma unroll
            for (int jp = 0; jp < 4; ++jp) {
                float4 d2 = *(const float4*)(pbase + jp * 4);
                float w0 = fmaxf(d2.x, tn * d2.y);
                float w1 = fmaxf(d2.z, tn * d2.w);
                int m0 = bit_mask(wq, 2 * jp);
                int m1 = bit_mask(wq, 2 * jp + 1);
                w0 = __uint_as_float(__float_as_uint(w0) & (unsigned int)m0);
                w1 = __uint_as_float(__float_as_uint(w1) & (unsigned int)m1);
                af.i[jp] = __builtin_amdgcn_perm(__float_as_uint(w1),
                                                 __float_as_uint(w0),
                                                 0x07060302u);
            }
            short8 b0 = *(const short8*)(hrow0 + mb);
            short8 b1 = *(const short8*)(hrow1 + mb);
            acc0 = __builtin_amdgcn_mfma_f32_16x16x32_bf16(af.s8, b0, acc0, 0, 0, 0);
            acc1 = __builtin_amdgcn_mfma_f32_16x16x32_bf16(af.s8, b1, acc1, 0, 0, 0);
            accd = __builtin_amdgcn_mfma_f32_16x16x32_bf16(af.s8, ones.s8, accd, 0, 0, 0);
        }
        __syncthreads();
        if (ck < 3) {
            int ckn = ck + 1;
#pragma unroll
            for (int k2 = 0; k2 < 4; ++k2) {
                int j = t + k2 * 512;
                int qq = j >> 9, jj = j & 511;
                int d = jj >> 4, c16 = jj & 15;
                int4 v = *(const int4*)(htp + (size_t)d * NN + qq * 512
                                        + ckn * 128 + c16 * 8);
                *(int4*)&hb[d * HBW + qq * QOF + c16 * 8] = v;
            }
        }
        __syncthreads();
    }

    // 4-way K-quarter reduction through LDS (alias hb as fp32 scratch; 18.4 KB)
    float* scr = (float*)hb;
    if (qt != 0) {
        int base = (((qt - 1) * 2 + ng) * 64 + lane) * 12;
        *(floatx4*)&scr[base + 0] = acc0;
        *(floatx4*)&scr[base + 4] = acc1;
        *(floatx4*)&scr[base + 8] = accd;
    }
    __syncthreads();
    if (qt == 0) {
#pragma unroll
        for (int p = 0; p < 3; ++p) {
            int base = ((p * 2 + ng) * 64 + lane) * 12;
            floatx4 p0 = *(const floatx4*)&scr[base + 0];
            floatx4 p1 = *(const floatx4*)&scr[base + 4];
            floatx4 pd = *(const floatx4*)&scr[base + 8];
#pragma unroll
            for (int k = 0; k < 4; ++k) {
                acc0[k] += p0[k]; acc1[k] += p1[k]; accd[k] += pd[k];
            }
        }
        // C/D layout: col = lane&15 (= r), row = q*4 + reg
#pragma unroll
        for (int reg = 0; reg < 4; ++reg) {
            int nrow = n0 + ng * 16 + q * 4 + reg;
            float inv = 1.0f / accd[reg];
            float* op = out + ((size_t)(b * NN + nrow)) * FF + head * DD;
            op[r]      = acc0[reg] * inv;
            op[16 + r] = acc1[reg] * inv;
        }
    }
}

extern "C" void kernel_launch(void* const* d_in, const int* in_sizes, int n_in,
                              void* d_out, int out_size, void* d_ws, size_t ws_size,
                              hipStream_t stream) {
    const float* x     = (const float*)d_in[0];
    const int*   adj   = (const int*)d_in[1];
    const float* W     = (const float*)d_in[2];
    const float* a_src = (const float*)d_in[3];
    const float* a_dst = (const float*)d_in[4];
    float* out = (float*)d_out;

    float* es_t = (float*)d_ws;                                   // 32,768 f
    float* ed_t = es_t + (size_t)BB * HH * NN;                    // 65,536 f (pairs)
    unsigned int* bits = (unsigned int*)(ed_t + (size_t)BB * HH * NN * 2); // 131,072 u32
    unsigned short* ht = (unsigned short*)(bits + (size_t)NN * (NN / 32)); // 2,097,152 bf16

    hipLaunchKernelGGL(k_prep, dim3(1024), dim3(256), 0, stream,
                       x, W, a_src, a_dst, adj, ht, es_t, ed_t, bits);
    hipLaunchKernelGGL(k_attn, dim3(NN / 32, BB * HH), dim3(512), 0, stream,
                       ht, bits, es_t, ed_t, out);
}

// Round 7
// 98.358 us; speedup vs baseline: 1.2527x; 1.2527x over previous
//
#include <hip/hip_runtime.h>
#include <math.h>

#define BB 4
#define NN 2048
#define FF 128
#define HH 4
#define DD 32
#define NEG_SLOPE 0.2f
#define LOG2E 1.4426950408889634f

typedef __attribute__((ext_vector_type(8))) short short8;
typedef __attribute__((ext_vector_type(4))) float floatx4;
typedef __attribute__((ext_vector_type(2))) float floatx2;

__device__ __forceinline__ float exp2_fast(float x) {
#if __has_builtin(__builtin_amdgcn_exp2f)
    return __builtin_amdgcn_exp2f(x);
#else
    return exp2f(x);
#endif
}

__device__ __forceinline__ int bit_mask(unsigned int w, int bit) {
#if __has_builtin(__builtin_amdgcn_sbfe)
    return __builtin_amdgcn_sbfe((int)w, bit, 1);    // v_bfe_i32: 0 or -1
#else
    return ((int)(w << (31 - bit))) >> 31;
#endif
}

// pack two fp32 -> one u32 holding (bf16(hi)<<16 | bf16(lo)), RTNE
__device__ __forceinline__ unsigned int pack2_rtne(float lo, float hi) {
    unsigned int ul = __float_as_uint(lo); ul += 0x7FFFu + ((ul >> 16) & 1u);
    unsigned int uh = __float_as_uint(hi); uh += 0x7FFFu + ((uh >> 16) & 1u);
    return (ul >> 16) | (uh & 0xFFFF0000u);
}

// ---------------- K1 (v2): prep = {gemm 32-row blocks 0..255, pack_adj 256..767}
// CHANGE vs R5: 32 rows per gemm block (was 16) -> 256 gemm blocks (was 512):
// halves the redundant W-staging/bf16-convert and the vs/vd recompute, which
// are per-block and row-independent. MFMA: each wave does 2 row-tiles x
// 2 col-tiles. es/ed: 8 lanes x 16 i per row (was 16 x 8).
__global__ __launch_bounds__(256) void k_prep(const float* __restrict__ x,
                                              const float* __restrict__ W,
                                              const float* __restrict__ a_src,
                                              const float* __restrict__ a_dst,
                                              const int* __restrict__ adj,
                                              unsigned short* __restrict__ ht,
                                              float* __restrict__ es_t,
                                              float* __restrict__ ed_t,
                                              unsigned int* __restrict__ bits) {
    __shared__ unsigned short wbf[128][144];   // 36.9 KB, W as bf16 [o][i]
    __shared__ unsigned short hbf[128][40];    // 10.2 KB, h^T bf16 [o][m_local 0..31]
    __shared__ float vs_s[HH][FF], vd_s[HH][FF];   // 4 KB
    __shared__ float as_s[FF], ad_s[FF];           // 1 KB
    int t = threadIdx.x;

    if (blockIdx.x >= 256) {
        // ---- pack_adj (verbatim; 512 blocks) ----
        int idx = (blockIdx.x - 256) * 256 + t;
        int n = idx >> 6, w = idx & 63;
        const int4* base = (const int4*)(adj + (size_t)n * NN + w * 32);
        unsigned int word = 0;
#pragma unroll
        for (int q = 0; q < 8; ++q) {
            int4 a = base[q];
            word |= ((unsigned int)(a.x & 1)) << (q * 4 + 0);
            word |= ((unsigned int)(a.y & 1)) << (q * 4 + 1);
            word |= ((unsigned int)(a.z & 1)) << (q * 4 + 2);
            word |= ((unsigned int)(a.w & 1)) << (q * 4 + 3);
        }
        bits[idx] = word;
        return;
    }

    int m0g = blockIdx.x * 32;
    int b = m0g >> 11;
    int m_block = m0g & 2047;

    if (t < FF) { as_s[t] = a_src[t]; ad_s[t] = a_dst[t]; }
    // stage W -> bf16 LDS: 2048 chunks of 8 shorts
#pragma unroll
    for (int k = 0; k < 8; ++k) {
        int idx = t + k * 256;
        int row = idx >> 4, ch = idx & 15;           // 16 chunks of 8 per row
        const float* wp = W + (size_t)row * FF + ch * 8;
        float4 v0 = *(const float4*)wp;
        float4 v1 = *(const float4*)(wp + 4);
        unsigned int u[4];
        u[0] = pack2_rtne(v0.x, v0.y); u[1] = pack2_rtne(v0.z, v0.w);
        u[2] = pack2_rtne(v1.x, v1.y); u[3] = pack2_rtne(v1.z, v1.w);
        *(int4*)&wbf[row][ch * 8] = *(const int4*)u;
    }
    __syncthreads();

    // per-head column sums: vs[h][i] = sum_d W[h*32+d][i]*a_src[h][d]
    {
        int i = t & 127;
        float acc4[4] = {0.f, 0.f, 0.f, 0.f};
        if (t < 128) {
            for (int o = 0; o < 128; ++o) {
                float wv = __uint_as_float(((unsigned int)wbf[o][i]) << 16);
                acc4[o >> 5] += wv * as_s[o];
            }
#pragma unroll
            for (int hd = 0; hd < 4; ++hd) vs_s[hd][i] = acc4[hd];
        } else {
            for (int o = 0; o < 128; ++o) {
                float wv = __uint_as_float(((unsigned int)wbf[o][i]) << 16);
                acc4[o >> 5] += wv * ad_s[o];
            }
#pragma unroll
            for (int hd = 0; hd < 4; ++hd) vd_s[hd][i] = acc4[hd];
        }
    }

    // MFMA: h[m0g..+31][0..127]; wave wid: col-tiles c=wid*2,wid*2+1 x row-tiles 0,1
    int wid = t >> 6, lane = t & 63;
    int r = lane & 15, q = lane >> 4;
    floatx4 acc[2][2] = {{{0.f,0.f,0.f,0.f},{0.f,0.f,0.f,0.f}},
                         {{0.f,0.f,0.f,0.f},{0.f,0.f,0.f,0.f}}};
    const float* xrow0 = x + (size_t)(m0g + r) * FF + q * 8;
    const float* xrow1 = x + (size_t)(m0g + 16 + r) * FF + q * 8;
#pragma unroll
    for (int kk = 0; kk < 4; ++kk) {
        union { short8 s8; unsigned int u[4]; } af0, af1;
        {
            float4 a0 = *(const float4*)(xrow0 + kk * 32);
            float4 a1 = *(const float4*)(xrow0 + kk * 32 + 4);
            af0.u[0] = pack2_rtne(a0.x, a0.y); af0.u[1] = pack2_rtne(a0.z, a0.w);
            af0.u[2] = pack2_rtne(a1.x, a1.y); af0.u[3] = pack2_rtne(a1.z, a1.w);
            float4 b0 = *(const float4*)(xrow1 + kk * 32);
            float4 b1 = *(const float4*)(xrow1 + kk * 32 + 4);
            af1.u[0] = pack2_rtne(b0.x, b0.y); af1.u[1] = pack2_rtne(b0.z, b0.w);
            af1.u[2] = pack2_rtne(b1.x, b1.y); af1.u[3] = pack2_rtne(b1.z, b1.w);
        }
#pragma unroll
        for (int c = 0; c < 2; ++c) {
            int o = (wid * 2 + c) * 16 + r;          // B col = lane&15
            short8 bf = *(const short8*)&wbf[o][kk * 32 + q * 8];
            acc[0][c] = __builtin_amdgcn_mfma_f32_16x16x32_bf16(af0.s8, bf, acc[0][c], 0, 0, 0);
            acc[1][c] = __builtin_amdgcn_mfma_f32_16x16x32_bf16(af1.s8, bf, acc[1][c], 0, 0, 0);
        }
    }
    // store h^T (bf16) to LDS: lane holds col o, rows rt*16 + q*4 + reg
#pragma unroll
    for (int rt = 0; rt < 2; ++rt) {
#pragma unroll
        for (int c = 0; c < 2; ++c) {
            int o = (wid * 2 + c) * 16 + r;
            unsigned int u2[2];
            u2[0] = pack2_rtne(acc[rt][c][0], acc[rt][c][1]);
            u2[1] = pack2_rtne(acc[rt][c][2], acc[rt][c][3]);
            *(int2*)&hbf[o][rt * 16 + q * 4] = *(const int2*)u2;
        }
    }
    __syncthreads();

    // ht write: thread t<128 handles col o=t -> ht[b*4+hd][d][m_block..+31]
    if (t < 128) {
        int hd = t >> 5, d = t & 31;
        unsigned short* op = ht + ((size_t)(b * HH + hd) * DD + d) * NN + m_block;
        *(int4*)op        = *(const int4*)&hbf[t][0];
        *(int4*)(op + 8)  = *(const int4*)&hbf[t][8];
        *(int4*)(op + 16) = *(const int4*)&hbf[t][16];
        *(int4*)(op + 24) = *(const int4*)&hbf[t][24];
    }
    // es/ed in fp32: thread (m = t>>3, sg = t&7), partial over i = sg*16..+15
    {
        int m = t >> 3, sg = t & 7;
        const float* xp = x + (size_t)(m0g + m) * FF + sg * 16;
        float4 x0 = *(const float4*)xp;
        float4 x1 = *(const float4*)(xp + 4);
        float4 x2 = *(const float4*)(xp + 8);
        float4 x3 = *(const float4*)(xp + 12);
#pragma unroll
        for (int hd = 0; hd < 4; ++hd) {
            const float* vsp = &vs_s[hd][sg * 16];
            const float* vdp = &vd_s[hd][sg * 16];
            float es = x0.x * vsp[0]  + x0.y * vsp[1]  + x0.z * vsp[2]  + x0.w * vsp[3]
                     + x1.x * vsp[4]  + x1.y * vsp[5]  + x1.z * vsp[6]  + x1.w * vsp[7]
                     + x2.x * vsp[8]  + x2.y * vsp[9]  + x2.z * vsp[10] + x2.w * vsp[11]
                     + x3.x * vsp[12] + x3.y * vsp[13] + x3.z * vsp[14] + x3.w * vsp[15];
            float ed = x0.x * vdp[0]  + x0.y * vdp[1]  + x0.z * vdp[2]  + x0.w * vdp[3]
                     + x1.x * vdp[4]  + x1.y * vdp[5]  + x1.z * vdp[6]  + x1.w * vdp[7]
                     + x2.x * vdp[8]  + x2.y * vdp[9]  + x2.z * vdp[10] + x2.w * vdp[11]
                     + x3.x * vdp[12] + x3.y * vdp[13] + x3.z * vdp[14] + x3.w * vdp[15];
#pragma unroll
            for (int k = 1; k < 8; k <<= 1) {
                es += __shfl_xor(es, k);
                ed += __shfl_xor(ed, k);
            }
            if (sg == 0) {
                size_t eb = (size_t)(b * HH + hd) * NN + m_block + m;
                es_t[eb] = es * LOG2E;
                float ee = ed * LOG2E;
                float2 pr;
                pr.x = exp2_fast(ee);
                pr.y = exp2_fast(NEG_SLOPE * ee);
                *(float2*)(ed_t + eb * 2) = pr;
            }
        }
    }
}

// ---------------- K2 (R5 VERBATIM, verified 98.27): co-resident 2 blocks/CU,
// 512 thr (8 waves = 4 n-groups x 2 K-halves, 64 rows/block), chunked hb.
#define HBW 528    // hb row stride in shorts
#define HOF 264    // half-1 column offset within a row (256 data + 8 pad)
__global__ __launch_bounds__(512) void k_attn(
        const unsigned short* __restrict__ ht,
        const unsigned int* __restrict__ bits,
        const float* __restrict__ es_t,
        const float* __restrict__ ed_t,
        float* __restrict__ out) {
    __shared__ unsigned short hb[DD * HBW];   // 33,792 B (chunk of both halves)
    __shared__ float ep[NN * 2];               // 16,384 B: (Ed_p, Ed_n) pairs
    int t = threadIdx.x;
    int n0 = blockIdx.x * 64;
    int bh = blockIdx.y;
    int b = bh >> 2, head = bh & 3;

    int wid = t >> 6, lane = t & 63;
    int q = lane >> 4, r = lane & 15;
    int qo = q * 8;
    int half = wid >> 2, wsub = wid & 3;
    int n_l = wsub * 16 + r;

    const unsigned short* htp = ht + (size_t)bh * DD * NN;

    // ep copy: 1024 float4 over 512 threads (pairs precomputed in k_prep)
    {
        const float4* src = (const float4*)(ed_t + (size_t)bh * NN * 2);
        ((float4*)ep)[t]       = src[t];
        ((float4*)ep)[t + 512] = src[t + 512];
    }
    // stage chunk 0: [32 d][256 m of each half] = 2048 int4 over 512 thr
#pragma unroll
    for (int k2 = 0; k2 < 4; ++k2) {
        int j = t + k2 * 512;
        int hf = j >> 10, jj = j & 1023;
        int d = jj >> 5, c16 = jj & 31;
        int4 v = *(const int4*)(htp + (size_t)d * NN + hf * 1024 + c16 * 8);
        *(int4*)&hb[d * HBW + hf * HOF + c16 * 8] = v;
    }
    float esv = es_t[(size_t)bh * NN + n0 + n_l];   // already * log2e
    float tn = exp2_fast(-0.8f * esv);              // es_n/es_p, row-constant
    __syncthreads();

    floatx4 acc0 = {0.f, 0.f, 0.f, 0.f};
    floatx4 acc1 = {0.f, 0.f, 0.f, 0.f};
    floatx4 accd = {0.f, 0.f, 0.f, 0.f};
    union { short8 s8; int i[4]; } ones;
    ones.i[0] = 0x3F803F80; ones.i[1] = 0x3F803F80;
    ones.i[2] = 0x3F803F80; ones.i[3] = 0x3F803F80;

    const unsigned short* hrow0 = &hb[r * HBW + half * HOF + qo];
    const unsigned short* hrow1 = &hb[(r + 16) * HBW + half * HOF + qo];
    const unsigned int* bpb = bits + (size_t)(n0 + n_l) * 64 + half * 32;

    for (int ck = 0; ck < 4; ++ck) {
        int4 bw0 = *(const int4*)(bpb + ck * 8);
        int4 bw1 = *(const int4*)(bpb + ck * 8 + 4);
        const float* pb_ck = ep + (half * 1024 + ck * 256) * 2;
#pragma unroll
        for (int g = 0; g < 2; ++g) {
            int4 bwv = g ? bw1 : bw0;
#pragma unroll
            for (int c = 0; c < 4; ++c) {
                unsigned int word = (unsigned int)((&bwv.x)[c]);
                int mb = g * 128 + c * 32;           // chunk-local m offset
                unsigned int wq = word >> qo;
                const float* pbase = pb_ck + (mb + qo) * 2;
                union { short8 s8; int i[4]; } af;
#pragma unroll
                for (int jp = 0; jp < 4; ++jp) {
                    float4 d2 = *(const float4*)(pbase + jp * 4);
                    float w0 = fmaxf(d2.x, tn * d2.y);
                    float w1 = fmaxf(d2.z, tn * d2.w);
                    int m0 = bit_mask(wq, 2 * jp);
                    int m1 = bit_mask(wq, 2 * jp + 1);
                    w0 = __uint_as_float(__float_as_uint(w0) & (unsigned int)m0);
                    w1 = __uint_as_float(__float_as_uint(w1) & (unsigned int)m1);
                    af.i[jp] = __builtin_amdgcn_perm(__float_as_uint(w1),
                                                     __float_as_uint(w0),
                                                     0x07060302u);
                }
                short8 b0 = *(const short8*)(hrow0 + mb);
                short8 b1 = *(const short8*)(hrow1 + mb);
                acc0 = __builtin_amdgcn_mfma_f32_16x16x32_bf16(af.s8, b0, acc0, 0, 0, 0);
                acc1 = __builtin_amdgcn_mfma_f32_16x16x32_bf16(af.s8, b1, acc1, 0, 0, 0);
                accd = __builtin_amdgcn_mfma_f32_16x16x32_bf16(af.s8, ones.s8, accd, 0, 0, 0);
            }
        }
        __syncthreads();
        if (ck < 3) {
            int ckn = ck + 1;
#pragma unroll
            for (int k2 = 0; k2 < 4; ++k2) {
                int j = t + k2 * 512;
                int hf = j >> 10, jj = j & 1023;
                int d = jj >> 5, c16 = jj & 31;
                int4 v = *(const int4*)(htp + (size_t)d * NN + hf * 1024
                                        + ckn * 256 + c16 * 8);
                *(int4*)&hb[d * HBW + hf * HOF + c16 * 8] = v;
            }
        }
        __syncthreads();
    }

    // K-half pair reduction through LDS (alias hb as fp32 scratch; 12.3 KB)
    float* scr = (float*)hb;
    if (half == 1) {
        int base = (wsub * 64 + lane) * 12;
        *(floatx4*)&scr[base + 0] = acc0;
        *(floatx4*)&scr[base + 4] = acc1;
        *(floatx4*)&scr[base + 8] = accd;
    }
    __syncthreads();
    if (half == 0) {
        int base = (wsub * 64 + lane) * 12;
        floatx4 p0 = *(const floatx4*)&scr[base + 0];
        floatx4 p1 = *(const floatx4*)&scr[base + 4];
        floatx4 pd = *(const floatx4*)&scr[base + 8];
#pragma unroll
        for (int k = 0; k < 4; ++k) {
            acc0[k] += p0[k]; acc1[k] += p1[k]; accd[k] += pd[k];
        }
        // C/D layout: col = lane&15 (= r), row = q*4 + reg
#pragma unroll
        for (int reg = 0; reg < 4; ++reg) {
            int nrow = n0 + wsub * 16 + q * 4 + reg;
            float inv = 1.0f / accd[reg];
            float* op = out + ((size_t)(b * NN + nrow)) * FF + head * DD;
            op[r]      = acc0[reg] * inv;
            op[16 + r] = acc1[reg] * inv;
        }
    }
}

extern "C" void kernel_launch(void* const* d_in, const int* in_sizes, int n_in,
                              void* d_out, int out_size, void* d_ws, size_t ws_size,
                              hipStream_t stream) {
    const float* x     = (const float*)d_in[0];
    const int*   adj   = (const int*)d_in[1];
    const float* W     = (const float*)d_in[2];
    const float* a_src = (const float*)d_in[3];
    const float* a_dst = (const float*)d_in[4];
    float* out = (float*)d_out;

    float* es_t = (float*)d_ws;                                   // 32,768 f
    float* ed_t = es_t + (size_t)BB * HH * NN;                    // 65,536 f (pairs)
    unsigned int* bits = (unsigned int*)(ed_t + (size_t)BB * HH * NN * 2); // 131,072 u32
    unsigned short* ht = (unsigned short*)(bits + (size_t)NN * (NN / 32)); // 2,097,152 bf16

    hipLaunchKernelGGL(k_prep, dim3(768), dim3(256), 0, stream,
                       x, W, a_src, a_dst, adj, ht, es_t, ed_t, bits);
    hipLaunchKernelGGL(k_attn, dim3(NN / 64, BB * HH), dim3(512), 0, stream,
                       ht, bits, es_t, ed_t, out);
}